// Round 4
// baseline (530.294 us; speedup 1.0000x reference)
//
#include <hip/hip_runtime.h>

// Pipeline: cvt(x,Wqkv,Wproj)->bf16 | bias_pre[H][257][257] (x log2e) |
//           gemm_qk (swapped-operand MFMA -> row-fragment epilogue, 8B stores)
//           gemm_v  (normal MFMA -> v^T scatter) |
//           attn_fused (S=QK^T bias-in-C, log2-softmax, O=PV, deferred norm) |
//           gemm_proj (swapped, float4 stores + proj_bias, fp32 out)
// GEMM core = R2 structure: 128x128 tile, BK=32, 16KB LDS, global_load_lds w=16.
// Swapped MFMA(bf,af,acc): lane holds (row m = wr+i*16+l15 fixed;
// cols c = wc+j*16+quad*4+r, r=0..3 consecutive) -> vectorizable stores.

typedef unsigned short u16;
typedef __attribute__((ext_vector_type(8))) short bf16x8;
typedef __attribute__((ext_vector_type(4))) float f32x4;

#define MFMA16(a, b, c) __builtin_amdgcn_mfma_f32_16x16x32_bf16(a, b, c, 0, 0, 0)
#define GLDS16(g, l)                                                           \
  __builtin_amdgcn_global_load_lds(                                            \
      (const __attribute__((address_space(1))) void*)(g),                      \
      (__attribute__((address_space(3))) void*)(l), 16, 0, 0)

// element offsets within qkv buffer
#define QOFF 0
#define KOFF 16842752
#define VTOFF 33685504
#define VTP 264  // v^T row pitch (elems), 528 B = 33*16
#define SCQ 0.18033688011112042f  // 64^-0.5 * log2(e)

__device__ __forceinline__ u16 f2bf(float f) {
  unsigned u = __builtin_bit_cast(unsigned, f);
  u += 0x7FFFu + ((u >> 16) & 1u);  // RNE; inputs are finite
  return (u16)(u >> 16);
}
__device__ __forceinline__ unsigned pack2(float a, float b) {
  return (unsigned)f2bf(a) | ((unsigned)f2bf(b) << 16);
}

// ---------------- fp32 -> bf16 convert (vectorized) ----------------
__global__ __launch_bounds__(256) void cvt_bf16(const float* __restrict__ in,
                                                u16* __restrict__ out, int n4) {
  int i = blockIdx.x * 256 + threadIdx.x;
  if (i < n4) {
    float4 v = ((const float4*)in)[i];
    uint2 o;
    o.x = pack2(v.x, v.y);
    o.y = pack2(v.z, v.w);
    ((uint2*)out)[i] = o;
  }
}

// ---- bias precompute: out[h][i][j] = table[idx[i][j]][h] * log2(e) ----
__global__ __launch_bounds__(256) void bias_pre(const float* __restrict__ tab,
                                                const int* __restrict__ idx,
                                                float* __restrict__ out) {
  int t = blockIdx.x * 256 + threadIdx.x;
  if (t < 66049) {
    int id = idx[t];
    const float* row = tab + (size_t)id * 16;
#pragma unroll
    for (int h = 0; h < 16; h++)
      out[(size_t)h * 66049 + t] = row[h] * 1.4426950408889634f;
  }
}

// ---------------- GEMM core (A[M,K] bf16, B[N,K] bf16, C=A.B^T) ------
// A must be padded to a multiple of 128 rows (garbage rows masked at store).

#define GEMM_KLOOP(K_, SW)                                                     \
  __shared__ __align__(16) u16 As[128 * 32];                                   \
  __shared__ __align__(16) u16 Bs[128 * 32];                                   \
  const int K = (K_);                                                          \
  const int tid = threadIdx.x;                                                 \
  const int lane = tid & 63, wave = tid >> 6;                                  \
  const int quad = lane >> 4, l15 = lane & 15;                                 \
  const int wr = (wave >> 1) * 64, wc = (wave & 1) * 64;                       \
  const int m0 = blockIdx.y * 128, n0 = blockIdx.x * 128;                      \
  const u16* pa0 = A + (size_t)(m0 + (tid >> 2)) * K + (tid & 3) * 8;          \
  const u16* pa1 = pa0 + (size_t)64 * K;                                       \
  const u16* pb0 = B + (size_t)(n0 + (tid >> 2)) * K + (tid & 3) * 8;          \
  const u16* pb1 = pb0 + (size_t)64 * K;                                       \
  f32x4 acc[4][4];                                                             \
  _Pragma("unroll") for (int i = 0; i < 4; i++)                                \
  _Pragma("unroll") for (int j = 0; j < 4; j++)                                \
      acc[i][j] = (f32x4){0.f, 0.f, 0.f, 0.f};                                 \
  for (int k0 = 0; k0 < K; k0 += 32) {                                         \
    __syncthreads();                                                           \
    GLDS16(pa0 + k0, As + tid * 8);                                            \
    GLDS16(pa1 + k0, As + 2048 + tid * 8);                                     \
    GLDS16(pb0 + k0, Bs + tid * 8);                                            \
    GLDS16(pb1 + k0, Bs + 2048 + tid * 8);                                     \
    __syncthreads();                                                           \
    bf16x8 af[4], bf[4];                                                       \
    _Pragma("unroll") for (int t = 0; t < 4; t++)                              \
        af[t] = *(const bf16x8*)(As + (wr + t * 16 + l15) * 32 + quad * 8);    \
    _Pragma("unroll") for (int t = 0; t < 4; t++)                              \
        bf[t] = *(const bf16x8*)(Bs + (wc + t * 16 + l15) * 32 + quad * 8);    \
    _Pragma("unroll") for (int i = 0; i < 4; i++)                              \
    _Pragma("unroll") for (int j = 0; j < 4; j++) {                            \
      if (SW)                                                                  \
        acc[i][j] = MFMA16(bf[j], af[i], acc[i][j]);                           \
      else                                                                     \
        acc[i][j] = MFMA16(af[i], bf[j], acc[i][j]);                           \
    }                                                                          \
  }

// q/k GEMM (swapped): cols 0..2047 = [q|k] -> [B][H][257][64] bf16, 8B stores.
__global__ __launch_bounds__(256) void gemm_qk(
    const u16* __restrict__ A, const u16* __restrict__ B,
    const float* __restrict__ qbias, u16* __restrict__ C) {
  GEMM_KLOOP(1024, 1)
#pragma unroll
  for (int i = 0; i < 4; i++) {
    int row = m0 + wr + i * 16 + l15;
    if (row < 16448) {
      unsigned bb = (unsigned)row / 257u;
      unsigned nn = (unsigned)row - bb * 257u;
      u16* Cr = C + (size_t)bb * (16 * 16448) + (size_t)nn * 64;
#pragma unroll
      for (int j = 0; j < 4; j++) {
        int c0 = n0 + wc + j * 16 + quad * 4;
        int rem0 = c0 & 1023;
        int h = rem0 >> 6, d0 = rem0 & 63;
        float v0, v1, v2, v3;
        if (c0 < 1024) {  // q: +bias, *scale (wave-uniform branch)
          float4 b4 = ((const float4*)qbias)[rem0 >> 2];
          v0 = (acc[i][j][0] + b4.x) * SCQ;
          v1 = (acc[i][j][1] + b4.y) * SCQ;
          v2 = (acc[i][j][2] + b4.z) * SCQ;
          v3 = (acc[i][j][3] + b4.w) * SCQ;
        } else {  // k: raw
          v0 = acc[i][j][0]; v1 = acc[i][j][1];
          v2 = acc[i][j][2]; v3 = acc[i][j][3];
        }
        uint2 pk;
        pk.x = pack2(v0, v1);
        pk.y = pack2(v2, v3);
        size_t off = (size_t)(c0 < 1024 ? QOFF : KOFF) + (size_t)h * 16448 + d0;
        *(uint2*)(Cr + off) = pk;
      }
    }
  }
}

// v GEMM (normal): B pre-offset to v cols; writes v^T [B][H][64][VTP].
__global__ __launch_bounds__(256) void gemm_v(
    const u16* __restrict__ A, const u16* __restrict__ B,
    const float* __restrict__ vbias, u16* __restrict__ C) {
  GEMM_KLOOP(1024, 0)
#pragma unroll
  for (int i = 0; i < 4; i++) {
    int row0 = m0 + wr + i * 16 + quad * 4;
#pragma unroll
    for (int r = 0; r < 4; r++) {
      int row = row0 + r;
      if (row < 16448) {
        unsigned bb = (unsigned)row / 257u;
        unsigned nn = (unsigned)row - bb * 257u;
#pragma unroll
        for (int j = 0; j < 4; j++) {
          int rem = n0 + wc + j * 16 + l15;
          int h = rem >> 6, d = rem & 63;
          float v = acc[i][j][r] + vbias[rem];
          C[(size_t)VTOFF + ((size_t)(bb * 16 + h) * 64 + d) * VTP + nn] =
              f2bf(v);
        }
      }
    }
  }
}

// Proj GEMM (swapped): fp32 out + proj_bias, row-major [16448][1024], float4.
__global__ __launch_bounds__(256) void gemm_proj(
    const u16* __restrict__ A, const u16* __restrict__ B,
    const float* __restrict__ pbias, float* __restrict__ C) {
  GEMM_KLOOP(1024, 1)
#pragma unroll
  for (int i = 0; i < 4; i++) {
    int row = m0 + wr + i * 16 + l15;
    if (row < 16448) {
#pragma unroll
      for (int j = 0; j < 4; j++) {
        int c0 = n0 + wc + j * 16 + quad * 4;
        float4 b4 = ((const float4*)pbias)[c0 >> 2];
        float4 o;
        o.x = acc[i][j][0] + b4.x;
        o.y = acc[i][j][1] + b4.y;
        o.z = acc[i][j][2] + b4.z;
        o.w = acc[i][j][3] + b4.w;
        *(float4*)(C + (size_t)row * 1024 + c0) = o;
      }
    }
  }
}

// ---------------- fused attention ----------------
// grid = B*H*5; block = 4 waves; wave owns 16 q-rows. Keys padded 257->288.
__global__ __launch_bounds__(256, 3) void attn_fused(
    const u16* __restrict__ qkv, const float* __restrict__ biasT,
    u16* __restrict__ out) {
  __shared__ __align__(16) u16 KVs[96 * 72];
  __shared__ __align__(16) u16 Ps[4 * 16 * 104];
  const int bx = blockIdx.x;
  const int qt = bx % 5, bh = bx / 5;
  const int b = bh >> 4, h = bh & 15;
  const int tid = threadIdx.x, lane = tid & 63, wave = tid >> 6;
  const int quad = lane >> 4, l15 = lane & 15;
  const u16* qg = qkv + QOFF + (size_t)bh * 16448;
  const u16* kg = qkv + KOFF + (size_t)bh * 16448;
  const u16* vtg = qkv + VTOFF + (size_t)bh * (64 * VTP);

  // Q fragments straight from global (rows clamped for the tail tile)
  int qra = qt * 64 + wave * 16 + l15;
  if (qra > 256) qra = 256;
  const bf16x8 aq0 = *(const bf16x8*)(qg + (size_t)qra * 64 + quad * 8);
  const bf16x8 aq1 = *(const bf16x8*)(qg + (size_t)qra * 64 + 32 + quad * 8);

  // bias -> accumulator init (C-layout); -3e38 masks pad cols through softmax
  const int qbase = qt * 64 + wave * 16 + quad * 4;
  const float* bb = biasT + (size_t)h * 66049;
  f32x4 s[18];
#pragma unroll
  for (int r = 0; r < 4; r++) {
    int qr = qbase + r;
    if (qr > 256) qr = 256;
    const float* brow = bb + (size_t)qr * 257;
#pragma unroll
    for (int t = 0; t < 18; t++) {
      int kc = t * 16 + l15;
      s[t][r] = (kc < 257) ? brow[kc] : -3e38f;
    }
  }

  // Phase 1: S += Q.K^T over 3 key chunks of 96
  const bf16x8 zv = {0, 0, 0, 0, 0, 0, 0, 0};
  for (int ck = 0; ck < 3; ck++) {
    __syncthreads();
#pragma unroll
    for (int it = 0; it < 3; it++) {
      int g = it * 256 + tid;  // 768 groups of 8 elems
      int row = g >> 3, col = (g & 7) * 8;
      int gr = ck * 96 + row;
      bf16x8 kv = (gr < 257) ? *(const bf16x8*)(kg + (size_t)gr * 64 + col) : zv;
      *(bf16x8*)(KVs + row * 72 + col) = kv;
    }
    __syncthreads();
#pragma unroll
    for (int nt = 0; nt < 6; nt++) {
      bf16x8 b0 = *(const bf16x8*)(KVs + (nt * 16 + l15) * 72 + quad * 8);
      bf16x8 b1 = *(const bf16x8*)(KVs + (nt * 16 + l15) * 72 + 32 + quad * 8);
      int t = ck * 6 + nt;
      s[t] = MFMA16(aq0, b0, s[t]);
      s[t] = MFMA16(aq1, b1, s[t]);
    }
  }

  // log2-domain softmax, normalization deferred to epilogue
  float inv[4];
#pragma unroll
  for (int r = 0; r < 4; r++) {
    float m = -3e38f;
#pragma unroll
    for (int t = 0; t < 18; t++) m = fmaxf(m, s[t][r]);
    m = fmaxf(m, __shfl_xor(m, 1));
    m = fmaxf(m, __shfl_xor(m, 2));
    m = fmaxf(m, __shfl_xor(m, 4));
    m = fmaxf(m, __shfl_xor(m, 8));
    float sum = 0.f;
#pragma unroll
    for (int t = 0; t < 18; t++) {
      float p = __builtin_amdgcn_exp2f(s[t][r] - m);
      s[t][r] = p;
      sum += p;
    }
    sum += __shfl_xor(sum, 1);
    sum += __shfl_xor(sum, 2);
    sum += __shfl_xor(sum, 4);
    sum += __shfl_xor(sum, 8);
    inv[r] = 1.f / sum;
  }

  // Phase 2: O = P.V^T-chunks; P written per-chunk (wave-private Ps region)
  u16* Pw = Ps + wave * (16 * 104);
  f32x4 o[4];
#pragma unroll
  for (int nt = 0; nt < 4; nt++) o[nt] = (f32x4){0.f, 0.f, 0.f, 0.f};
  for (int ck = 0; ck < 3; ck++) {
    __syncthreads();
#pragma unroll
    for (int it = 0; it < 3; it++) {
      int g = it * 256 + tid;       // 768 groups: [64 d][12 col-groups]
      int row = g / 12, c = (g % 12) * 8;
      bf16x8 v = *(const bf16x8*)(vtg + (size_t)row * VTP + ck * 96 + c);
      *(bf16x8*)(KVs + row * 104 + c) = v;  // pad cols: finite garbage; P=0 there
    }
#pragma unroll
    for (int nt = 0; nt < 6; nt++) {
      int t = ck * 6 + nt;
#pragma unroll
      for (int r = 0; r < 4; r++)
        Pw[(quad * 4 + r) * 104 + nt * 16 + l15] = f2bf(s[t][r]);
    }
    __syncthreads();
#pragma unroll
    for (int ks = 0; ks < 3; ks++) {
      bf16x8 ap = *(const bf16x8*)(Pw + l15 * 104 + ks * 32 + quad * 8);
#pragma unroll
      for (int nt = 0; nt < 4; nt++) {
        bf16x8 bv =
            *(const bf16x8*)(KVs + (nt * 16 + l15) * 104 + ks * 32 + quad * 8);
        o[nt] = MFMA16(ap, bv, o[nt]);
      }
    }
  }

  // store O -> attn_out [B][257][H*64] bf16 (normalize here)
#pragma unroll
  for (int nt = 0; nt < 4; nt++) {
    int d = nt * 16 + l15;
#pragma unroll
    for (int r = 0; r < 4; r++) {
      int qr = qbase + r;
      if (qr < 257)
        out[((size_t)b * 257 + qr) * 1024 + h * 64 + d] =
            f2bf(o[nt][r] * inv[r]);
    }
  }
}

// ---------------- launch ----------------
extern "C" void kernel_launch(void* const* d_in, const int* in_sizes, int n_in,
                              void* d_out, int out_size, void* d_ws,
                              size_t ws_size, hipStream_t stream) {
  const float* x = (const float*)d_in[0];
  const float* qkvw = (const float*)d_in[1];
  const float* qb = (const float*)d_in[2];
  const float* vb = (const float*)d_in[3];
  const float* tab = (const float*)d_in[4];
  const float* pw = (const float*)d_in[5];
  const float* pb = (const float*)d_in[6];
  const int* rpi = (const int*)d_in[7];

  char* ws = (char*)d_ws;
  u16* qkvbuf = (u16*)ws;                    // q|k|v^T bf16, 101,974,016 B
  u16* xbuf = (u16*)(ws + 101974016);        // x bf16 padded to 16512 rows,
                                             // reused as attn_out (33,816,576 B)
  float* biasb = (float*)(ws + 135790592);   // [16][257][257] f32*log2e, 4,227,136 B
  u16* qkvwb = (u16*)(ws + 140017728);       // 6,291,456 B
  u16* projwb = (u16*)(ws + 146309184);      // 2,097,152 B; end 148,406,336

  cvt_bf16<<<16448, 256, 0, stream>>>(x, xbuf, 4210688);
  cvt_bf16<<<3072, 256, 0, stream>>>(qkvw, qkvwb, 786432);
  cvt_bf16<<<1024, 256, 0, stream>>>(pw, projwb, 262144);
  bias_pre<<<259, 256, 0, stream>>>(tab, rpi, biasb);
  gemm_qk<<<dim3(16, 129), 256, 0, stream>>>(xbuf, qkvwb, qb, qkvbuf);
  gemm_v<<<dim3(8, 129), 256, 0, stream>>>(xbuf, qkvwb + (size_t)2048 * 1024,
                                           vb, qkvbuf);
  attn_fused<<<5120, 256, 0, stream>>>(qkvbuf, biasb, xbuf);
  gemm_proj<<<dim3(8, 129), 256, 0, stream>>>(xbuf, projwb, pb, (float*)d_out);
}

// Round 5
// 466.146 us; speedup vs baseline: 1.1376x; 1.1376x over previous
//
#include <hip/hip_runtime.h>

// Pipeline: cvt(x,Wqkv,Wproj)->bf16 | bias_pre[H][257][257] (x log2e) |
//           gemm_qkv (bf16 MFMA; q*(0.125*log2e)+qb, k, v+vb -> v^T layout) |
//           attn_fused (S=QK^T with bias-in-C, log2-softmax, O=PV, defer norm) |
//           gemm_proj (+proj_bias, fp32 out)
// GEMM core: R2 structure (128x128 tile, BK=32, 16KB LDS, VGPR~76) + XOR
// bank swizzle WITHIN the 32-elem row: k-group g of row r lives at slot
// g ^ ((r>>1)&3). Staging keeps lane-contiguous LDS dest (global_load_lds
// requirement) with per-lane permuted SOURCE k-offset; fragment reads add
// one setup XOR. Per-half-wave bank coverage is exactly even -> conflict-free
// at zero VGPR/occupancy cost (R3 got 0 conflicts but paid occupancy; R4
// confirmed occupancy >> all else).

typedef unsigned short u16;
typedef __attribute__((ext_vector_type(8))) short bf16x8;
typedef __attribute__((ext_vector_type(4))) float f32x4;

#define MFMA16(a, b, c) __builtin_amdgcn_mfma_f32_16x16x32_bf16(a, b, c, 0, 0, 0)
#define GLDS16(g, l)                                                           \
  __builtin_amdgcn_global_load_lds(                                            \
      (const __attribute__((address_space(1))) void*)(g),                      \
      (__attribute__((address_space(3))) void*)(l), 16, 0, 0)

// element offsets within qkv buffer
#define QOFF 0
#define KOFF 16842752
#define VTOFF 33685504
#define VTP 264  // v^T row pitch (elems), 528 B = 33*16

__device__ __forceinline__ u16 f2bf(float f) {
  unsigned u = __builtin_bit_cast(unsigned, f);
  u += 0x7FFFu + ((u >> 16) & 1u);  // RNE; inputs are finite
  return (u16)(u >> 16);
}
__device__ __forceinline__ unsigned pack2(float a, float b) {
  return (unsigned)f2bf(a) | ((unsigned)f2bf(b) << 16);
}

// ---------------- fp32 -> bf16 convert (vectorized) ----------------
__global__ __launch_bounds__(256) void cvt_bf16(const float* __restrict__ in,
                                                u16* __restrict__ out, int n4) {
  int i = blockIdx.x * 256 + threadIdx.x;
  if (i < n4) {
    float4 v = ((const float4*)in)[i];
    uint2 o;
    o.x = pack2(v.x, v.y);
    o.y = pack2(v.z, v.w);
    ((uint2*)out)[i] = o;
  }
}

// ---- bias precompute: out[h][i][j] = table[idx[i][j]][h] * log2(e) ----
__global__ __launch_bounds__(256) void bias_pre(const float* __restrict__ tab,
                                                const int* __restrict__ idx,
                                                float* __restrict__ out) {
  int t = blockIdx.x * 256 + threadIdx.x;
  if (t < 66049) {
    int id = idx[t];
    const float* row = tab + (size_t)id * 16;
#pragma unroll
    for (int h = 0; h < 16; h++)
      out[(size_t)h * 66049 + t] = row[h] * 1.4426950408889634f;
  }
}

// ---------------- GEMM core (A[M,K] bf16, B[N,K] bf16, C=A.B^T) ------
// 128x128 tile, BK=32, 256 thr (4 waves 2x2 of 64x64), 16x16x32 MFMA.
// LDS row = 32 elems; 16B-group g of row r stored at slot g^((r>>1)&3).

#define GEMM_PROLOG(M_, K_)                                                    \
  __shared__ __align__(16) u16 As[128 * 32];                                   \
  __shared__ __align__(16) u16 Bs[128 * 32];                                   \
  const int M = (M_), K = (K_);                                                \
  const int tid = threadIdx.x;                                                 \
  const int lane = tid & 63, wave = tid >> 6;                                  \
  const int quad = lane >> 4, l15 = lane & 15;                                 \
  const int wr = (wave >> 1) * 64, wc = (wave & 1) * 64;                       \
  const int m0 = blockIdx.y * 128, n0 = blockIdx.x * 128;                      \
  const int sgk = (((tid & 3) ^ ((tid >> 3) & 3))) * 8; /* staged src k-off */ \
  const int fo = ((quad ^ ((l15 >> 1) & 3))) * 8;       /* frag read k-off */  \
  int ar0 = m0 + (tid >> 2); if (ar0 > M - 1) ar0 = M - 1;                     \
  int ar1 = m0 + 64 + (tid >> 2); if (ar1 > M - 1) ar1 = M - 1;                \
  const u16* pa0 = A + (size_t)ar0 * K + sgk;                                  \
  const u16* pa1 = A + (size_t)ar1 * K + sgk;                                  \
  const u16* pb0 = B + (size_t)(n0 + (tid >> 2)) * K + sgk;                    \
  const u16* pb1 = pb0 + (size_t)64 * K;                                       \
  f32x4 acc[4][4];                                                             \
  _Pragma("unroll") for (int i = 0; i < 4; i++)                                \
  _Pragma("unroll") for (int j = 0; j < 4; j++)                                \
      acc[i][j] = (f32x4){0.f, 0.f, 0.f, 0.f};                                 \
  for (int k0 = 0; k0 < K; k0 += 32) {                                         \
    __syncthreads();                                                           \
    GLDS16(pa0 + k0, As + tid * 8);                                            \
    GLDS16(pa1 + k0, As + 2048 + tid * 8);                                     \
    GLDS16(pb0 + k0, Bs + tid * 8);                                            \
    GLDS16(pb1 + k0, Bs + 2048 + tid * 8);                                     \
    __syncthreads();                                                           \
    bf16x8 af[4], bf[4];                                                       \
    _Pragma("unroll") for (int t = 0; t < 4; t++)                              \
        af[t] = *(const bf16x8*)(As + (wr + t * 16 + l15) * 32 + fo);          \
    _Pragma("unroll") for (int t = 0; t < 4; t++)                              \
        bf[t] = *(const bf16x8*)(Bs + (wc + t * 16 + l15) * 32 + fo);          \
    _Pragma("unroll") for (int i = 0; i < 4; i++)                              \
    _Pragma("unroll") for (int j = 0; j < 4; j++)                              \
        acc[i][j] = MFMA16(af[i], bf[j], acc[i][j]);                           \
  }

// QKV GEMM: cols [q|k|v]; q,k -> [B][H][257][64]; v -> v^T [B][H][64][VTP].
__global__ __launch_bounds__(256) void gemm_qkv(
    const u16* __restrict__ A, const u16* __restrict__ B,
    const float* __restrict__ qbias, const float* __restrict__ vbias,
    u16* __restrict__ C) {
  GEMM_PROLOG(16448, 1024)
#pragma unroll
  for (int i = 0; i < 4; i++) {
#pragma unroll
    for (int r = 0; r < 4; r++) {
      int row = m0 + wr + i * 16 + quad * 4 + r;
      if (row < M) {
        unsigned bb = (unsigned)row / 257u;
        unsigned nn = (unsigned)row - bb * 257u;
#pragma unroll
        for (int j = 0; j < 4; j++) {
          int c = n0 + wc + j * 16 + l15;
          int which = c >> 10, rem = c & 1023;
          float bias = (which == 0) ? qbias[rem]
                                    : ((which == 2) ? vbias[rem] : 0.f);
          float v = acc[i][j][r] + bias;
          if (which == 0) v *= 0.18033688011112042f;  // 64^-0.5 * log2(e)
          int h = rem >> 6, d = rem & 63;
          size_t dst;
          if (which == 2) {
            dst = (size_t)VTOFF + ((size_t)(bb * 16 + h) * 64 + d) * VTP + nn;
          } else {
            dst = (size_t)which * 16842752 + (size_t)(bb * 16 + h) * 16448 +
                  (size_t)nn * 64 + d;
          }
          C[dst] = f2bf(v);
        }
      }
    }
  }
}

// Proj GEMM: fp32 out + proj_bias, row-major [16448][1024].
__global__ __launch_bounds__(256) void gemm_proj(
    const u16* __restrict__ A, const u16* __restrict__ B,
    const float* __restrict__ pbias, float* __restrict__ C) {
  GEMM_PROLOG(16448, 1024)
#pragma unroll
  for (int i = 0; i < 4; i++) {
#pragma unroll
    for (int r = 0; r < 4; r++) {
      int row = m0 + wr + i * 16 + quad * 4 + r;
      if (row < M) {
#pragma unroll
        for (int j = 0; j < 4; j++) {
          int c = n0 + wc + j * 16 + l15;
          C[(size_t)row * 1024 + c] = acc[i][j][r] + pbias[c];
        }
      }
    }
  }
}

// ---------------- fused attention ----------------
// grid = B*H*5; block = 4 waves; wave owns 16 q-rows. Keys padded 257->288.
__global__ __launch_bounds__(256, 3) void attn_fused(
    const u16* __restrict__ qkv, const float* __restrict__ biasT,
    u16* __restrict__ out) {
  __shared__ __align__(16) u16 KVs[96 * 72];
  __shared__ __align__(16) u16 Ps[4 * 16 * 104];
  const int bx = blockIdx.x;
  const int qt = bx % 5, bh = bx / 5;
  const int b = bh >> 4, h = bh & 15;
  const int tid = threadIdx.x, lane = tid & 63, wave = tid >> 6;
  const int quad = lane >> 4, l15 = lane & 15;
  const u16* qg = qkv + QOFF + (size_t)bh * 16448;
  const u16* kg = qkv + KOFF + (size_t)bh * 16448;
  const u16* vtg = qkv + VTOFF + (size_t)bh * (64 * VTP);

  // Q fragments straight from global (rows clamped for the tail tile)
  int qra = qt * 64 + wave * 16 + l15;
  if (qra > 256) qra = 256;
  const bf16x8 aq0 = *(const bf16x8*)(qg + (size_t)qra * 64 + quad * 8);
  const bf16x8 aq1 = *(const bf16x8*)(qg + (size_t)qra * 64 + 32 + quad * 8);

  // bias -> accumulator init (C-layout); -3e38 masks pad cols through softmax
  const int qbase = qt * 64 + wave * 16 + quad * 4;
  const float* bb = biasT + (size_t)h * 66049;
  f32x4 s[18];
#pragma unroll
  for (int r = 0; r < 4; r++) {
    int qr = qbase + r;
    if (qr > 256) qr = 256;
    const float* brow = bb + (size_t)qr * 257;
#pragma unroll
    for (int t = 0; t < 18; t++) {
      int kc = t * 16 + l15;
      s[t][r] = (kc < 257) ? brow[kc] : -3e38f;
    }
  }

  // Phase 1: S += Q.K^T over 3 key chunks of 96
  const bf16x8 zv = {0, 0, 0, 0, 0, 0, 0, 0};
  for (int ck = 0; ck < 3; ck++) {
    __syncthreads();
#pragma unroll
    for (int it = 0; it < 3; it++) {
      int g = it * 256 + tid;  // 768 groups of 8 elems
      int row = g >> 3, col = (g & 7) * 8;
      int gr = ck * 96 + row;
      bf16x8 kv = (gr < 257) ? *(const bf16x8*)(kg + (size_t)gr * 64 + col) : zv;
      *(bf16x8*)(KVs + row * 72 + col) = kv;
    }
    __syncthreads();
#pragma unroll
    for (int nt = 0; nt < 6; nt++) {
      bf16x8 b0 = *(const bf16x8*)(KVs + (nt * 16 + l15) * 72 + quad * 8);
      bf16x8 b1 = *(const bf16x8*)(KVs + (nt * 16 + l15) * 72 + 32 + quad * 8);
      int t = ck * 6 + nt;
      s[t] = MFMA16(aq0, b0, s[t]);
      s[t] = MFMA16(aq1, b1, s[t]);
    }
  }

  // log2-domain softmax, normalization deferred to epilogue
  float inv[4];
#pragma unroll
  for (int r = 0; r < 4; r++) {
    float m = -3e38f;
#pragma unroll
    for (int t = 0; t < 18; t++) m = fmaxf(m, s[t][r]);
    m = fmaxf(m, __shfl_xor(m, 1));
    m = fmaxf(m, __shfl_xor(m, 2));
    m = fmaxf(m, __shfl_xor(m, 4));
    m = fmaxf(m, __shfl_xor(m, 8));
    float sum = 0.f;
#pragma unroll
    for (int t = 0; t < 18; t++) {
      float p = __builtin_amdgcn_exp2f(s[t][r] - m);
      s[t][r] = p;
      sum += p;
    }
    sum += __shfl_xor(sum, 1);
    sum += __shfl_xor(sum, 2);
    sum += __shfl_xor(sum, 4);
    sum += __shfl_xor(sum, 8);
    inv[r] = 1.f / sum;
  }

  // Phase 2: O = P.V^T-chunks; P written per-chunk (wave-private Ps region)
  u16* Pw = Ps + wave * (16 * 104);
  f32x4 o[4];
#pragma unroll
  for (int nt = 0; nt < 4; nt++) o[nt] = (f32x4){0.f, 0.f, 0.f, 0.f};
  for (int ck = 0; ck < 3; ck++) {
    __syncthreads();
#pragma unroll
    for (int it = 0; it < 3; it++) {
      int g = it * 256 + tid;       // 768 groups: [64 d][12 col-groups]
      int row = g / 12, c = (g % 12) * 8;
      bf16x8 v = *(const bf16x8*)(vtg + (size_t)row * VTP + ck * 96 + c);
      *(bf16x8*)(KVs + row * 104 + c) = v;  // pad cols: finite garbage; P=0 there
    }
#pragma unroll
    for (int nt = 0; nt < 6; nt++) {
      int t = ck * 6 + nt;
#pragma unroll
      for (int r = 0; r < 4; r++)
        Pw[(quad * 4 + r) * 104 + nt * 16 + l15] = f2bf(s[t][r]);
    }
    __syncthreads();
#pragma unroll
    for (int ks = 0; ks < 3; ks++) {
      bf16x8 ap = *(const bf16x8*)(Pw + l15 * 104 + ks * 32 + quad * 8);
#pragma unroll
      for (int nt = 0; nt < 4; nt++) {
        bf16x8 bv =
            *(const bf16x8*)(KVs + (nt * 16 + l15) * 104 + ks * 32 + quad * 8);
        o[nt] = MFMA16(ap, bv, o[nt]);
      }
    }
  }

  // store O -> attn_out [B][257][H*64] bf16 (normalize here)
#pragma unroll
  for (int nt = 0; nt < 4; nt++) {
    int d = nt * 16 + l15;
#pragma unroll
    for (int r = 0; r < 4; r++) {
      int qr = qbase + r;
      if (qr < 257)
        out[((size_t)b * 257 + qr) * 1024 + h * 64 + d] =
            f2bf(o[nt][r] * inv[r]);
    }
  }
}

// ---------------- launch ----------------
extern "C" void kernel_launch(void* const* d_in, const int* in_sizes, int n_in,
                              void* d_out, int out_size, void* d_ws,
                              size_t ws_size, hipStream_t stream) {
  const float* x = (const float*)d_in[0];
  const float* qkvw = (const float*)d_in[1];
  const float* qb = (const float*)d_in[2];
  const float* vb = (const float*)d_in[3];
  const float* tab = (const float*)d_in[4];
  const float* pw = (const float*)d_in[5];
  const float* pb = (const float*)d_in[6];
  const int* rpi = (const int*)d_in[7];

  char* ws = (char*)d_ws;
  u16* qkvbuf = (u16*)ws;                    // q|k|v^T bf16, 101,974,016 B
  u16* xbuf = (u16*)(ws + 101974016);        // x bf16, reused as attn_out (33,685,504 B)
  float* biasb = (float*)(ws + 135659520);   // [16][257][257] f32 *log2e, 4,227,136 B
  u16* qkvwb = (u16*)(ws + 139886656);       // 6,291,456 B
  u16* projwb = (u16*)(ws + 146178112);      // 2,097,152 B; end 148,275,264

  cvt_bf16<<<16448, 256, 0, stream>>>(x, xbuf, 4210688);
  cvt_bf16<<<3072, 256, 0, stream>>>(qkvw, qkvwb, 786432);
  cvt_bf16<<<1024, 256, 0, stream>>>(pw, projwb, 262144);
  bias_pre<<<259, 256, 0, stream>>>(tab, rpi, biasb);
  gemm_qkv<<<dim3(24, 129), 256, 0, stream>>>(xbuf, qkvwb, qb, vb, qkvbuf);
  attn_fused<<<5120, 256, 0, stream>>>(qkvbuf, biasb, xbuf);
  gemm_proj<<<dim3(8, 129), 256, 0, stream>>>(xbuf, projwb, pb, (float*)d_out);
}